// Round 1
// baseline (838.430 us; speedup 1.0000x reference)
//
#include <hip/hip_runtime.h>
#include <math.h>

#define BB 16
#define LL 1024
#define DD 128
#define BL (BB*LL)
#define KK 16
#define NDEPTH 4
#define EPSF 1e-5f

// ---------------------------------------------------------------- lift
// H[b,l,d] = sum_c lift_w[d,c]*x[b,c,l] + lift_w[d,3]*coord(l) + lift_b[d]
__global__ __launch_bounds__(256) void lift_kernel(const float* __restrict__ x,
        const float* __restrict__ lw, const float* __restrict__ lb,
        float* __restrict__ H) {
    int idx = blockIdx.x * 256 + threadIdx.x;   // BL*DD threads
    int d = idx & 127;
    int tok = idx >> 7;
    int b = tok >> 10, l = tok & 1023;
    const float* xb = x + (size_t)b * 3 * LL + l;
    float coord = (float)l * (1.0f / 1023.0f);
    float v = lb[d];
    v += lw[d*4 + 0] * xb[0];
    v += lw[d*4 + 1] * xb[LL];
    v += lw[d*4 + 2] * xb[2*LL];
    v += lw[d*4 + 3] * coord;
    H[(size_t)tok * DD + d] = v;
}

// ---------------------------------------------------------------- LayerNorm over d (one wave per token)
__global__ __launch_bounds__(256) void ln_kernel(const float* __restrict__ H,
        const float* __restrict__ g, const float* __restrict__ bta,
        float* __restrict__ Z) {
    int wave = threadIdx.x >> 6;
    int lane = threadIdx.x & 63;
    int tok = blockIdx.x * 4 + wave;
    const float* hp = H + (size_t)tok * DD;
    float2 hv = *(const float2*)(hp + lane * 2);
    float s  = hv.x + hv.y;
    float sq = hv.x * hv.x + hv.y * hv.y;
    #pragma unroll
    for (int o = 32; o >= 1; o >>= 1) {
        s  += __shfl_xor(s,  o, 64);
        sq += __shfl_xor(sq, o, 64);
    }
    float mu  = s * (1.0f / 128.0f);
    float var = sq * (1.0f / 128.0f) - mu * mu;
    float rstd = rsqrtf(var + EPSF);
    float2 gv = *(const float2*)(g   + lane * 2);
    float2 bv = *(const float2*)(bta + lane * 2);
    float2 z;
    z.x = (hv.x - mu) * rstd * gv.x + bv.x;
    z.y = (hv.y - mu) * rstd * gv.y + bv.y;
    *(float2*)(Z + (size_t)tok * DD + lane * 2) = z;
}

// ---------------------------------------------------------------- column sum of Z over l (partials, deterministic)
__global__ __launch_bounds__(128) void zsum_kernel(const float* __restrict__ Z,
        float* __restrict__ Zpart) {
    int d = threadIdx.x;       // 128
    int chunk = blockIdx.x;    // 8
    int b = blockIdx.y;        // 16
    const float* zp = Z + ((size_t)b * LL + chunk * 128) * DD + d;
    float s = 0.f;
    #pragma unroll 4
    for (int l = 0; l < 128; ++l) s += zp[(size_t)l * DD];
    Zpart[(b * 8 + chunk) * 128 + d] = s;
}

// ---------------------------------------------------------------- C[b,h] = (1/sqrt(L)) * sum_d theta0[h,d] * Zsum[b,d]
__global__ __launch_bounds__(128) void c_kernel(const float* __restrict__ theta_l,
        const float* __restrict__ Zpart, float* __restrict__ C) {
    __shared__ float zs[128];
    int b = blockIdx.x;
    int h = threadIdx.x;
    float s = 0.f;
    #pragma unroll
    for (int c = 0; c < 8; ++c) s += Zpart[(b * 8 + c) * 128 + h];
    zs[h] = s;
    __syncthreads();
    const float* th = theta_l + h * DD;   // k = 0 slab
    float acc = 0.f;
    #pragma unroll 4
    for (int d = 0; d < DD; d += 4) {
        float4 t = *(const float4*)(th + d);
        acc += t.x * zs[d] + t.y * zs[d+1] + t.z * zs[d+2] + t.w * zs[d+3];
    }
    C[b * DD + h] = acc * (1.0f / 32.0f);   // 1/sqrt(1024)
}

// ---------------------------------------------------------------- S kernel (fused Haar conv)
// S[b,h,n] = C[b,h] + sum_{k=1..15} sum_d theta[k,h,d] * dz[b,d,(n+2k-2)%L]
// dz[m] = (z[m]-z[m+1])/sqrt(2).  Block: 64 tokens x 128 h outputs.
#define DZP 100
__global__ __launch_bounds__(256) void s_kernel(const float* __restrict__ Z,
        const float* __restrict__ theta_l, const float* __restrict__ C,
        float* __restrict__ S) {
    __shared__ float dzs[128 * DZP];
    int b  = blockIdx.y;
    int n0 = blockIdx.x * 64;
    int tid = threadIdx.x;
    const float* Zb = Z + (size_t)b * LL * DD;
    const float inv_s2 = 0.70710678118654752f;

    // stage dz halo tile: rows m = 0..91 (local), transposed [d][m]
    for (int li = tid; li < 92 * 128; li += 256) {
        int r = li >> 7, d = li & 127;
        int gr  = (n0 + r) & (LL - 1);
        int gr1 = (n0 + r + 1) & (LL - 1);
        float za = Zb[(size_t)gr  * DD + d];
        float zb = Zb[(size_t)gr1 * DD + d];
        dzs[d * DZP + r] = (za - zb) * inv_s2;
    }
    __syncthreads();

    int hg = tid >> 3, ng = tid & 7;
    int h0 = hg * 4, nb = ng * 8;
    float acc[8][4];
    #pragma unroll
    for (int j = 0; j < 8; ++j)
        #pragma unroll
        for (int i = 0; i < 4; ++i) acc[j][i] = 0.f;

    for (int k = 1; k < 16; ++k) {
        const float* th = theta_l + k * DD * DD + h0 * DD;
        int mo = nb + 2 * (k - 1);
        for (int d = 0; d < 128; d += 4) {
            float t4[4][4];
            *(float4*)t4[0] = *(const float4*)(th + 0 * DD + d);
            *(float4*)t4[1] = *(const float4*)(th + 1 * DD + d);
            *(float4*)t4[2] = *(const float4*)(th + 2 * DD + d);
            *(float4*)t4[3] = *(const float4*)(th + 3 * DD + d);
            #pragma unroll
            for (int dd = 0; dd < 4; ++dd) {
                const float* row = &dzs[(d + dd) * DZP + mo];
                float v[8];
                *(float2*)&v[0] = *(const float2*)(row + 0);
                *(float2*)&v[2] = *(const float2*)(row + 2);
                *(float2*)&v[4] = *(const float2*)(row + 4);
                *(float2*)&v[6] = *(const float2*)(row + 6);
                #pragma unroll
                for (int j = 0; j < 8; ++j)
                    #pragma unroll
                    for (int i = 0; i < 4; ++i)
                        acc[j][i] += v[j] * t4[i][dd];
            }
        }
    }

    float4 c4 = *(const float4*)(C + b * DD + h0);
    #pragma unroll
    for (int j = 0; j < 8; ++j) {
        float4 o;
        o.x = acc[j][0] + c4.x;
        o.y = acc[j][1] + c4.y;
        o.z = acc[j][2] + c4.z;
        o.w = acc[j][3] + c4.w;
        *(float4*)(S + ((size_t)b * LL + n0 + nb + j) * DD + h0) = o;
    }
}

// ---------------------------------------------------------------- fc1 + exact GELU
// H1[t,m] = gelu(sum_d fc1_w[m,d]*S[t,d] + fc1_b[m]), m in [0,256)
#define XS1 68
__global__ __launch_bounds__(256) void fc1_kernel(const float* __restrict__ S,
        const float* __restrict__ w, const float* __restrict__ bias,
        float* __restrict__ H1) {
    __shared__ float xs[128 * XS1];
    int t0 = blockIdx.x * 64;
    int mbase = blockIdx.y * 128;
    int tid = threadIdx.x;
    for (int li = tid; li < 64 * 128; li += 256) {
        int t = li >> 7, d = li & 127;
        xs[d * XS1 + t] = S[((size_t)t0 + t) * DD + d];
    }
    __syncthreads();
    int og = tid >> 3, ng = tid & 7;
    int m0 = mbase + og * 4;
    int tb = ng * 8;
    float acc[8][4];
    #pragma unroll
    for (int j = 0; j < 8; ++j)
        #pragma unroll
        for (int i = 0; i < 4; ++i) acc[j][i] = 0.f;

    for (int d = 0; d < 128; d += 4) {
        float t4[4][4];
        *(float4*)t4[0] = *(const float4*)(w + (size_t)(m0 + 0) * DD + d);
        *(float4*)t4[1] = *(const float4*)(w + (size_t)(m0 + 1) * DD + d);
        *(float4*)t4[2] = *(const float4*)(w + (size_t)(m0 + 2) * DD + d);
        *(float4*)t4[3] = *(const float4*)(w + (size_t)(m0 + 3) * DD + d);
        #pragma unroll
        for (int dd = 0; dd < 4; ++dd) {
            float v[8];
            *(float4*)&v[0] = *(const float4*)(&xs[(d + dd) * XS1 + tb]);
            *(float4*)&v[4] = *(const float4*)(&xs[(d + dd) * XS1 + tb + 4]);
            #pragma unroll
            for (int j = 0; j < 8; ++j)
                #pragma unroll
                for (int i = 0; i < 4; ++i)
                    acc[j][i] += v[j] * t4[i][dd];
        }
    }
    float4 b4 = *(const float4*)(bias + m0);
    float bb[4] = {b4.x, b4.y, b4.z, b4.w};
    #pragma unroll
    for (int j = 0; j < 8; ++j) {
        float4 o;
        float xv, gv;
        xv = acc[j][0] + bb[0]; gv = 0.5f * xv * (1.0f + erff(xv * 0.70710678f)); o.x = gv;
        xv = acc[j][1] + bb[1]; gv = 0.5f * xv * (1.0f + erff(xv * 0.70710678f)); o.y = gv;
        xv = acc[j][2] + bb[2]; gv = 0.5f * xv * (1.0f + erff(xv * 0.70710678f)); o.z = gv;
        xv = acc[j][3] + bb[3]; gv = 0.5f * xv * (1.0f + erff(xv * 0.70710678f)); o.w = gv;
        *(float4*)(H1 + ((size_t)t0 + tb + j) * 256 + m0) = o;
    }
}

// ---------------------------------------------------------------- fc2 + residual into H
// H[t,d] += sum_m fc2_w[d,m]*H1[t,m] + fc2_b[d]
#define XS2 36
__global__ __launch_bounds__(256) void fc2_kernel(const float* __restrict__ H1,
        const float* __restrict__ w, const float* __restrict__ bias,
        float* __restrict__ H) {
    __shared__ float xs[256 * XS2];
    int t0 = blockIdx.x * 32;
    int tid = threadIdx.x;
    for (int li = tid; li < 32 * 256; li += 256) {
        int t = li >> 8, m = li & 255;
        xs[m * XS2 + t] = H1[((size_t)t0 + t) * 256 + m];
    }
    __syncthreads();
    int og = tid >> 3, ng = tid & 7;
    int d0 = og * 4, tb = ng * 4;
    float acc[4][4];
    #pragma unroll
    for (int j = 0; j < 4; ++j)
        #pragma unroll
        for (int i = 0; i < 4; ++i) acc[j][i] = 0.f;

    for (int m = 0; m < 256; m += 4) {
        float t4[4][4];
        *(float4*)t4[0] = *(const float4*)(w + (size_t)(d0 + 0) * 256 + m);
        *(float4*)t4[1] = *(const float4*)(w + (size_t)(d0 + 1) * 256 + m);
        *(float4*)t4[2] = *(const float4*)(w + (size_t)(d0 + 2) * 256 + m);
        *(float4*)t4[3] = *(const float4*)(w + (size_t)(d0 + 3) * 256 + m);
        #pragma unroll
        for (int mm = 0; mm < 4; ++mm) {
            float4 v = *(const float4*)(&xs[(m + mm) * XS2 + tb]);
            float vv[4] = {v.x, v.y, v.z, v.w};
            #pragma unroll
            for (int j = 0; j < 4; ++j)
                #pragma unroll
                for (int i = 0; i < 4; ++i)
                    acc[j][i] += vv[j] * t4[i][mm];
        }
    }
    float4 b4 = *(const float4*)(bias + d0);
    #pragma unroll
    for (int j = 0; j < 4; ++j) {
        float* hp = H + ((size_t)t0 + tb + j) * DD + d0;
        float4 r = *(float4*)hp;
        r.x += acc[j][0] + b4.x;
        r.y += acc[j][1] + b4.y;
        r.z += acc[j][2] + b4.z;
        r.w += acc[j][3] + b4.w;
        *(float4*)hp = r;
    }
}

// ---------------------------------------------------------------- head (one wave per token)
__global__ __launch_bounds__(256) void head_kernel(const float* __restrict__ H,
        const float* __restrict__ hw, const float* __restrict__ hb,
        float* __restrict__ out) {
    int wave = threadIdx.x >> 6, lane = threadIdx.x & 63;
    int tok = blockIdx.x * 4 + wave;
    float2 hv = *(const float2*)(H + (size_t)tok * DD + lane * 2);
    float2 wv = *(const float2*)(hw + lane * 2);
    float s = hv.x * wv.x + hv.y * wv.y;
    #pragma unroll
    for (int o = 32; o >= 1; o >>= 1) s += __shfl_xor(s, o, 64);
    if (lane == 0) out[tok] = s + hb[0];
}

// ----------------------------------------------------------------
extern "C" void kernel_launch(void* const* d_in, const int* in_sizes, int n_in,
                              void* d_out, int out_size, void* d_ws, size_t ws_size,
                              hipStream_t stream) {
    const float* x     = (const float*)d_in[0];
    const float* lw    = (const float*)d_in[1];
    const float* lb    = (const float*)d_in[2];
    // d_in[3] = Phi_f (complex64) — analytically eliminated (Haar top-16 = const + 2-tap wavelets)
    const float* theta = (const float*)d_in[4];
    const float* ln_g  = (const float*)d_in[5];
    const float* ln_b  = (const float*)d_in[6];
    const float* fc1w  = (const float*)d_in[7];
    const float* fc1b  = (const float*)d_in[8];
    const float* fc2w  = (const float*)d_in[9];
    const float* fc2b  = (const float*)d_in[10];
    const float* hw    = (const float*)d_in[11];
    const float* hb    = (const float*)d_in[12];

    float* ws = (float*)d_ws;
    float* H  = ws;                                   // BL*DD
    float* Z  = H  + (size_t)BL * DD;                 // BL*DD
    float* Sb = Z  + (size_t)BL * DD;                 // BL*DD
    float* H1 = Sb + (size_t)BL * DD;                 // BL*2*DD
    float* Zp = H1 + (size_t)BL * 2 * DD;             // 16*8*128
    float* Cb = Zp + 16 * 8 * 128;                    // 16*128

    lift_kernel<<<BL * DD / 256, 256, 0, stream>>>(x, lw, lb, H);

    for (int i = 0; i < NDEPTH; ++i) {
        const float* th = theta + (size_t)i * KK * DD * DD;
        ln_kernel<<<BL / 4, 256, 0, stream>>>(H, ln_g + i * DD, ln_b + i * DD, Z);
        zsum_kernel<<<dim3(8, 16), 128, 0, stream>>>(Z, Zp);
        c_kernel<<<16, 128, 0, stream>>>(th, Zp, Cb);
        s_kernel<<<dim3(LL / 64, BB), 256, 0, stream>>>(Z, th, Cb, Sb);
        fc1_kernel<<<dim3(BL / 64, 2), 256, 0, stream>>>(Sb, fc1w + (size_t)i * 2 * DD * DD,
                                                         fc1b + (size_t)i * 2 * DD, H1);
        fc2_kernel<<<BL / 32, 256, 0, stream>>>(H1, fc2w + (size_t)i * DD * 2 * DD,
                                                fc2b + (size_t)i * DD, H);
    }
    head_kernel<<<BL / 4, 256, 0, stream>>>(H, hw, hb, (float*)d_out);
}

// Round 2
// 264.840 us; speedup vs baseline: 3.1658x; 3.1658x over previous
//
#include <hip/hip_runtime.h>
#include <math.h>

#define BB 16
#define LL 1024
#define DD 128
#define BL (BB*LL)
#define NDEPTH 4
#define EPSF 1e-5f

typedef unsigned short u16;
typedef short bf16x8 __attribute__((ext_vector_type(8)));
typedef short bf16x4 __attribute__((ext_vector_type(4)));
typedef float f32x4 __attribute__((ext_vector_type(4)));

static __device__ __forceinline__ u16 f2bf(float x) {
    unsigned u = __float_as_uint(x);
    u = u + 0x7fffu + ((u >> 16) & 1u);
    return (u16)(u >> 16);
}

// ---------------------------------------------------------------- weight converts
// theta: f32 [4][16][128][128] -> bf16 [layer*15+kk][128][128] (k=0 skipped),
// PRE-SWIZZLED in-row so a linear LDS copy yields the swizzled layout.
__global__ __launch_bounds__(256) void cvt_theta(const float* __restrict__ theta,
        u16* __restrict__ out) {
    int idx = blockIdx.x * 256 + threadIdx.x;      // 4*15*128*128
    int d = idx & 127;
    int h = (idx >> 7) & 127;
    int slab = idx >> 14;                          // 0..59
    int layer = slab / 15, kk = slab - layer * 15;
    float v = theta[(((size_t)layer * 16 + kk + 1) * 128 + h) * 128 + d];
    int byte = (d * 2) ^ ((h & 7) << 4);
    out[(size_t)slab * 16384 + h * 128 + (byte >> 1)] = f2bf(v);
}

__global__ __launch_bounds__(256) void cvt_f32_bf16(const float* __restrict__ src,
        u16* __restrict__ dst, int n) {
    int idx = blockIdx.x * 256 + threadIdx.x;
    if (idx < n) dst[idx] = f2bf(src[idx]);
}

// ---------------------------------------------------------------- lift
__global__ __launch_bounds__(256) void lift_kernel(const float* __restrict__ x,
        const float* __restrict__ lw, const float* __restrict__ lb,
        float* __restrict__ H) {
    int idx = blockIdx.x * 256 + threadIdx.x;
    int d = idx & 127;
    int tok = idx >> 7;
    int b = tok >> 10, l = tok & 1023;
    const float* xb = x + (size_t)b * 3 * LL + l;
    float coord = (float)l * (1.0f / 1023.0f);
    float v = lb[d];
    v += lw[d*4 + 0] * xb[0];
    v += lw[d*4 + 1] * xb[LL];
    v += lw[d*4 + 2] * xb[2*LL];
    v += lw[d*4 + 3] * coord;
    H[(size_t)tok * DD + d] = v;
}

// ---------------------------------------------------------------- LayerNorm over d
__global__ __launch_bounds__(256) void ln_kernel(const float* __restrict__ H,
        const float* __restrict__ g, const float* __restrict__ bta,
        float* __restrict__ Z) {
    int wave = threadIdx.x >> 6;
    int lane = threadIdx.x & 63;
    int tok = blockIdx.x * 4 + wave;
    const float* hp = H + (size_t)tok * DD;
    float2 hv = *(const float2*)(hp + lane * 2);
    float s  = hv.x + hv.y;
    float sq = hv.x * hv.x + hv.y * hv.y;
    #pragma unroll
    for (int o = 32; o >= 1; o >>= 1) {
        s  += __shfl_xor(s,  o, 64);
        sq += __shfl_xor(sq, o, 64);
    }
    float mu  = s * (1.0f / 128.0f);
    float var = sq * (1.0f / 128.0f) - mu * mu;
    float rstd = rsqrtf(var + EPSF);
    float2 gv = *(const float2*)(g   + lane * 2);
    float2 bv = *(const float2*)(bta + lane * 2);
    float2 z;
    z.x = (hv.x - mu) * rstd * gv.x + bv.x;
    z.y = (hv.y - mu) * rstd * gv.y + bv.y;
    *(float2*)(Z + (size_t)tok * DD + lane * 2) = z;
}

// ---------------------------------------------------------------- column partial sums of Z
__global__ __launch_bounds__(128) void zsum_kernel(const float* __restrict__ Z,
        float* __restrict__ Zpart) {
    int d = threadIdx.x;
    int chunk = blockIdx.x;
    int b = blockIdx.y;
    const float* zp = Z + ((size_t)b * LL + chunk * 128) * DD + d;
    float s = 0.f;
    #pragma unroll 4
    for (int l = 0; l < 128; ++l) s += zp[(size_t)l * DD];
    Zpart[(b * 8 + chunk) * 128 + d] = s;
}

// ---------------------------------------------------------------- C[b,h] (k=0 Haar row, f32)
__global__ __launch_bounds__(128) void c_kernel(const float* __restrict__ theta_l,
        const float* __restrict__ Zpart, float* __restrict__ C) {
    __shared__ float zs[128];
    int b = blockIdx.x;
    int h = threadIdx.x;
    float s = 0.f;
    #pragma unroll
    for (int c = 0; c < 8; ++c) s += Zpart[(b * 8 + c) * 128 + h];
    zs[h] = s;
    __syncthreads();
    const float* th = theta_l + h * DD;
    float acc = 0.f;
    #pragma unroll 4
    for (int d = 0; d < DD; d += 4) {
        float4 t = *(const float4*)(th + d);
        acc += t.x * zs[d] + t.y * zs[d+1] + t.z * zs[d+2] + t.w * zs[d+3];
    }
    C[b * DD + h] = acc * (1.0f / 32.0f);
}

// ---------------------------------------------------------------- S via MFMA
// S[b,h,n] = C[b,h] + sum_{kk=0..14} sum_d th[kk,h,d] * dz[b,d,n+2kk]
// Block: 128h x 64tok. 4 waves: wave tile 64h x 32tok (4x2 16x16 frags).
#define DZ_BYTES 23552          // 92 rows * 256B
__global__ __launch_bounds__(256) void s_mfma_kernel(const float* __restrict__ Z,
        const u16* __restrict__ thbf, const float* __restrict__ C,
        u16* __restrict__ Sbf) {
    __shared__ char lds[DZ_BYTES + 32768];
    int b = blockIdx.y, n0 = blockIdx.x * 64;
    int tid = threadIdx.x;
    const float* Zb = Z + (size_t)b * LL * DD;

    // ---- stage dz (92 rows x 128 d, bf16, XOR-swizzled rows of 256B)
    for (int c = tid; c < 92 * 16; c += 256) {
        int r = c >> 4, d0 = (c & 15) * 8;
        int gr  = (n0 + r) & (LL - 1);
        int gr1 = (n0 + r + 1) & (LL - 1);
        const float* za = Zb + (size_t)gr  * DD + d0;
        const float* zc = Zb + (size_t)gr1 * DD + d0;
        u16 tmp[8];
        #pragma unroll
        for (int j = 0; j < 8; ++j)
            tmp[j] = f2bf((za[j] - zc[j]) * 0.70710678118654752f);
        int byte = r * 256 + ((d0 * 2) ^ ((r & 7) << 4));
        *(bf16x8*)(lds + byte) = *(bf16x8*)tmp;
    }

    // ---- theta slab prefetch registers (slab = 16384 u16, pre-swizzled in global)
    bf16x8 pre[8];
    {
        const u16* src = thbf;
        #pragma unroll
        for (int c = 0; c < 8; ++c)
            pre[c] = *(const bf16x8*)(src + (size_t)(tid + c * 256) * 8);
    }
    #pragma unroll
    for (int c = 0; c < 8; ++c)
        *(bf16x8*)(lds + DZ_BYTES + (size_t)(tid + c * 256) * 16) = pre[c];
    __syncthreads();

    int wave = tid >> 6, lane = tid & 63;
    int hw0 = (wave & 1) * 64;
    int tw0 = (wave >> 1) * 32;
    int lm = lane & 15, lk = (lane >> 4) * 8;

    f32x4 zero4 = {0.f, 0.f, 0.f, 0.f};
    f32x4 acc[4][2];
    #pragma unroll
    for (int mt = 0; mt < 4; ++mt)
        #pragma unroll
        for (int nt = 0; nt < 2; ++nt) acc[mt][nt] = zero4;

    for (int kk = 0; kk < 15; ++kk) {
        if (kk < 14) {                       // issue next-slab loads early (T14)
            const u16* src = thbf + (size_t)(kk + 1) * 16384;
            #pragma unroll
            for (int c = 0; c < 8; ++c)
                pre[c] = *(const bf16x8*)(src + (size_t)(tid + c * 256) * 8);
        }
        #pragma unroll
        for (int d0 = 0; d0 < 128; d0 += 32) {
            bf16x8 bfr[2], afr[4];
            #pragma unroll
            for (int nt = 0; nt < 2; ++nt) {
                int trow = tw0 + nt * 16 + lm + 2 * kk;
                int byte = trow * 256 + (((d0 + lk) * 2) ^ ((trow & 7) << 4));
                bfr[nt] = *(const bf16x8*)(lds + byte);
            }
            #pragma unroll
            for (int mt = 0; mt < 4; ++mt) {
                int h = hw0 + mt * 16 + lm;
                int byte = DZ_BYTES + h * 256 + (((d0 + lk) * 2) ^ ((h & 7) << 4));
                afr[mt] = *(const bf16x8*)(lds + byte);
            }
            #pragma unroll
            for (int mt = 0; mt < 4; ++mt)
                #pragma unroll
                for (int nt = 0; nt < 2; ++nt)
                    acc[mt][nt] = __builtin_amdgcn_mfma_f32_16x16x32_bf16(
                        afr[mt], bfr[nt], acc[mt][nt], 0, 0, 0);
        }
        __syncthreads();
        if (kk < 14) {
            #pragma unroll
            for (int c = 0; c < 8; ++c)
                *(bf16x8*)(lds + DZ_BYTES + (size_t)(tid + c * 256) * 16) = pre[c];
            __syncthreads();
        }
    }

    // ---- epilogue: + C[b,h], bf16, transpose via LDS, coalesced 16B stores
    const float* Cb = C + b * DD;
    #pragma unroll
    for (int mt = 0; mt < 4; ++mt) {
        int h0 = hw0 + mt * 16 + (lane >> 4) * 4;
        #pragma unroll
        for (int nt = 0; nt < 2; ++nt) {
            int tl = tw0 + nt * 16 + lm;
            u16 o[4];
            #pragma unroll
            for (int r = 0; r < 4; ++r)
                o[r] = f2bf(acc[mt][nt][r] + Cb[h0 + r]);
            int byte = DZ_BYTES + tl * 256 + ((h0 * 2) ^ ((tl & 7) << 4));
            *(bf16x4*)(lds + byte) = *(bf16x4*)o;
        }
    }
    __syncthreads();
    u16* Sp = Sbf + ((size_t)b * LL + n0) * DD;
    for (int c = tid; c < 64 * 16; c += 256) {
        int r = c >> 4, d0 = (c & 15) * 8;
        int byte = DZ_BYTES + r * 256 + ((d0 * 2) ^ ((r & 7) << 4));
        *(bf16x8*)(Sp + (size_t)r * DD + d0) = *(const bf16x8*)(lds + byte);
    }
}

// ---------------------------------------------------------------- fused MLP: fc1+GELU+fc2+residual
// Block: 64 tokens, all channels. fc1: wave m-split (64 m each), fc2: wave d-split (32 d each).
__global__ __launch_bounds__(256) void mlp_kernel(const u16* __restrict__ Sbf,
        const u16* __restrict__ w1, const float* __restrict__ b1,
        const u16* __restrict__ w2, const float* __restrict__ b2,
        float* __restrict__ H) {
    __shared__ char lds[16384 + 32768];     // Sx[64][256B] swz | H1t[64][512B] swz
    int t0 = blockIdx.x * 64;
    int tid = threadIdx.x;

    for (int c = tid; c < 64 * 16; c += 256) {
        int r = c >> 4, d0 = (c & 15) * 8;
        bf16x8 v = *(const bf16x8*)(Sbf + (size_t)(t0 + r) * DD + d0);
        int byte = r * 256 + ((d0 * 2) ^ ((r & 7) << 4));
        *(bf16x8*)(lds + byte) = v;
    }
    __syncthreads();

    int wave = tid >> 6, lane = tid & 63;
    int lm = lane & 15, lk = (lane >> 4) * 8;
    f32x4 zero4 = {0.f, 0.f, 0.f, 0.f};

    // ---- fc1: out 256m x 64t, K=128
    int m0 = wave * 64;
    f32x4 acc1[4][4];
    #pragma unroll
    for (int mt = 0; mt < 4; ++mt)
        #pragma unroll
        for (int nt = 0; nt < 4; ++nt) acc1[mt][nt] = zero4;
    #pragma unroll
    for (int d0 = 0; d0 < 128; d0 += 32) {
        bf16x8 bfr[4], afr[4];
        #pragma unroll
        for (int nt = 0; nt < 4; ++nt) {
            int tl = nt * 16 + lm;
            int byte = tl * 256 + (((d0 + lk) * 2) ^ ((tl & 7) << 4));
            bfr[nt] = *(const bf16x8*)(lds + byte);
        }
        #pragma unroll
        for (int mt = 0; mt < 4; ++mt) {
            int m = m0 + mt * 16 + lm;
            afr[mt] = *(const bf16x8*)(w1 + (size_t)m * DD + d0 + lk);
        }
        #pragma unroll
        for (int mt = 0; mt < 4; ++mt)
            #pragma unroll
            for (int nt = 0; nt < 4; ++nt)
                acc1[mt][nt] = __builtin_amdgcn_mfma_f32_16x16x32_bf16(
                    afr[mt], bfr[nt], acc1[mt][nt], 0, 0, 0);
    }
    // gelu -> H1 tile (bf16, swizzled 512B rows)
    #pragma unroll
    for (int mt = 0; mt < 4; ++mt) {
        int mo = m0 + mt * 16 + (lane >> 4) * 4;
        f32x4 bb4 = *(const f32x4*)(b1 + mo);
        #pragma unroll
        for (int nt = 0; nt < 4; ++nt) {
            int tl = nt * 16 + lm;
            u16 o[4];
            #pragma unroll
            for (int r = 0; r < 4; ++r) {
                float xv = acc1[mt][nt][r] + bb4[r];
                float gv = 0.5f * xv * (1.0f + erff(xv * 0.70710678118654752f));
                o[r] = f2bf(gv);
            }
            int byte = 16384 + tl * 512 + ((mo * 2) ^ ((tl & 7) << 4));
            *(bf16x4*)(lds + byte) = *(bf16x4*)o;
        }
    }
    __syncthreads();

    // ---- fc2: out 128d x 64t, K=256
    int dw = wave * 32;
    f32x4 acc2[2][4];
    #pragma unroll
    for (int mt = 0; mt < 2; ++mt)
        #pragma unroll
        for (int nt = 0; nt < 4; ++nt) acc2[mt][nt] = zero4;
    #pragma unroll
    for (int mk = 0; mk < 256; mk += 32) {
        bf16x8 bfr[4], afr[2];
        #pragma unroll
        for (int nt = 0; nt < 4; ++nt) {
            int tl = nt * 16 + lm;
            int byte = 16384 + tl * 512 + (((mk + lk) * 2) ^ ((tl & 7) << 4));
            bfr[nt] = *(const bf16x8*)(lds + byte);
        }
        #pragma unroll
        for (int mt = 0; mt < 2; ++mt) {
            int d = dw + mt * 16 + lm;
            afr[mt] = *(const bf16x8*)(w2 + (size_t)d * 256 + mk + lk);
        }
        #pragma unroll
        for (int mt = 0; mt < 2; ++mt)
            #pragma unroll
            for (int nt = 0; nt < 4; ++nt)
                acc2[mt][nt] = __builtin_amdgcn_mfma_f32_16x16x32_bf16(
                    afr[mt], bfr[nt], acc2[mt][nt], 0, 0, 0);
    }
    __syncthreads();    // done reading H1t; reuse as f32 Ht[64][512B] swz

    #pragma unroll
    for (int mt = 0; mt < 2; ++mt) {
        int dbase = dw + mt * 16 + (lane >> 4) * 4;
        #pragma unroll
        for (int nt = 0; nt < 4; ++nt) {
            int tl = nt * 16 + lm;
            int byte = 16384 + tl * 512 + ((dbase * 4) ^ ((tl & 7) << 4));
            *(f32x4*)(lds + byte) = acc2[mt][nt];
        }
    }
    __syncthreads();
    for (int c = tid; c < 64 * 32; c += 256) {
        int r = c >> 5, d0 = (c & 31) * 4;
        int byte = 16384 + r * 512 + ((d0 * 4) ^ ((r & 7) << 4));
        f32x4 v = *(const f32x4*)(lds + byte);
        f32x4 bb = *(const f32x4*)(b2 + d0);
        float* hp = H + (size_t)(t0 + r) * DD + d0;
        f32x4 hv = *(const f32x4*)hp;
        hv = hv + v + bb;
        *(f32x4*)hp = hv;
    }
}

// ---------------------------------------------------------------- head
__global__ __launch_bounds__(256) void head_kernel(const float* __restrict__ H,
        const float* __restrict__ hw, const float* __restrict__ hb,
        float* __restrict__ out) {
    int wave = threadIdx.x >> 6, lane = threadIdx.x & 63;
    int tok = blockIdx.x * 4 + wave;
    float2 hv = *(const float2*)(H + (size_t)tok * DD + lane * 2);
    float2 wv = *(const float2*)(hw + lane * 2);
    float s = hv.x * wv.x + hv.y * wv.y;
    #pragma unroll
    for (int o = 32; o >= 1; o >>= 1) s += __shfl_xor(s, o, 64);
    if (lane == 0) out[tok] = s + hb[0];
}

// ----------------------------------------------------------------
extern "C" void kernel_launch(void* const* d_in, const int* in_sizes, int n_in,
                              void* d_out, int out_size, void* d_ws, size_t ws_size,
                              hipStream_t stream) {
    const float* x     = (const float*)d_in[0];
    const float* lw    = (const float*)d_in[1];
    const float* lb    = (const float*)d_in[2];
    // d_in[3] = Phi_f — analytically eliminated (Haar top-16 = const + finest 2-tap wavelets)
    const float* theta = (const float*)d_in[4];
    const float* ln_g  = (const float*)d_in[5];
    const float* ln_b  = (const float*)d_in[6];
    const float* fc1w  = (const float*)d_in[7];
    const float* fc1b  = (const float*)d_in[8];
    const float* fc2w  = (const float*)d_in[9];
    const float* fc2b  = (const float*)d_in[10];
    const float* hw    = (const float*)d_in[11];
    const float* hb    = (const float*)d_in[12];

    float* ws = (float*)d_ws;
    float* H  = ws;                                    // 2M f32
    float* Z  = H + (size_t)BL * DD;                   // 2M f32
    float* Zp = Z + (size_t)BL * DD;                   // 16*8*128
    float* Cb = Zp + 16 * 8 * 128;                     // 16*128
    u16* u16base = (u16*)(Cb + 16 * 128);
    u16* Sbf = u16base;                                // BL*DD
    u16* thb = Sbf + (size_t)BL * DD;                  // 4*15*128*128
    u16* w1b = thb + (size_t)4 * 15 * 128 * 128;       // 4*256*128
    u16* w2b = w1b + (size_t)4 * 256 * 128;            // 4*128*256

    cvt_theta<<<4 * 15 * 128 * 128 / 256, 256, 0, stream>>>(theta, thb);
    cvt_f32_bf16<<<512, 256, 0, stream>>>(fc1w, w1b, 4 * 256 * 128);
    cvt_f32_bf16<<<512, 256, 0, stream>>>(fc2w, w2b, 4 * 128 * 256);

    lift_kernel<<<BL * DD / 256, 256, 0, stream>>>(x, lw, lb, H);

    for (int i = 0; i < NDEPTH; ++i) {
        const float* th_f32 = theta + (size_t)i * 16 * 128 * 128;
        ln_kernel<<<BL / 4, 256, 0, stream>>>(H, ln_g + i * DD, ln_b + i * DD, Z);
        zsum_kernel<<<dim3(8, 16), 128, 0, stream>>>(Z, Zp);
        c_kernel<<<16, 128, 0, stream>>>(th_f32, Zp, Cb);
        s_mfma_kernel<<<dim3(LL / 64, BB), 256, 0, stream>>>(
            Z, thb + (size_t)i * 15 * 16384, Cb, Sbf);
        mlp_kernel<<<BL / 64, 256, 0, stream>>>(
            Sbf, w1b + (size_t)i * 32768, fc1b + (size_t)i * 256,
            w2b + (size_t)i * 32768, fc2b + (size_t)i * 128, H);
    }
    head_kernel<<<BL / 4, 256, 0, stream>>>(H, hw, hb, (float*)d_out);
}

// Round 3
// 244.149 us; speedup vs baseline: 3.4341x; 1.0847x over previous
//
#include <hip/hip_runtime.h>
#include <math.h>

#define BB 16
#define LL 1024
#define DD 128
#define BL (BB*LL)
#define NDEPTH 4
#define EPSF 1e-5f

typedef unsigned short u16;
typedef short bf16x8 __attribute__((ext_vector_type(8)));
typedef short bf16x4 __attribute__((ext_vector_type(4)));
typedef float f32x4 __attribute__((ext_vector_type(4)));

static __device__ __forceinline__ u16 f2bf(float x) {
    unsigned u = __float_as_uint(x);
    u = u + 0x7fffu + ((u >> 16) & 1u);
    return (u16)(u >> 16);
}

// ---------------------------------------------------------------- combined weight convert
// theta -> frag-linear bf16 [slab=layer*15+kk][f:8][c:4][lane:64][8]
//   value = theta[layer][kk+1][h=f*16+(ln&15)][d=32c+8*(ln>>4)+j]
// w1 -> [layer][f:16][c:4][lane][8]  = fc1w[layer][m=f*16+lm][d=32c+8hi+j]
// w2 -> [layer][f:8][c:8][lane][8]   = fc2w[layer][d=f*16+lm][m=32c+8hi+j]
#define N_TH (4*15*16384)
#define N_W1 (4*32768)
#define N_W2 (4*32768)
__global__ __launch_bounds__(256) void cvt_kernel(const float* __restrict__ theta,
        const float* __restrict__ fc1w, const float* __restrict__ fc2w,
        u16* __restrict__ thf, u16* __restrict__ w1f, u16* __restrict__ w2f) {
    int o = blockIdx.x * 256 + threadIdx.x;
    if (o < N_TH) {
        int j = o & 7, ln = (o >> 3) & 63, c = (o >> 9) & 3, f = (o >> 11) & 7;
        int slab = o >> 14;
        int layer = slab / 15, kk = slab - layer * 15;
        int h = f * 16 + (ln & 15), d = 32 * c + 8 * (ln >> 4) + j;
        thf[o] = f2bf(theta[(((size_t)layer * 16 + kk + 1) * 128 + h) * 128 + d]);
    } else if (o < N_TH + N_W1) {
        int o2 = o - N_TH;
        int j = o2 & 7, ln = (o2 >> 3) & 63, c = (o2 >> 9) & 3, f = (o2 >> 11) & 15;
        int layer = o2 >> 15;
        int m = f * 16 + (ln & 15), d = 32 * c + 8 * (ln >> 4) + j;
        w1f[o2] = f2bf(fc1w[(size_t)layer * 32768 + m * 128 + d]);
    } else if (o < N_TH + N_W1 + N_W2) {
        int o2 = o - (N_TH + N_W1);
        int j = o2 & 7, ln = (o2 >> 3) & 63, c = (o2 >> 9) & 7, f = (o2 >> 12) & 7;
        int layer = o2 >> 15;
        int d = f * 16 + (ln & 15), m = 32 * c + 8 * (ln >> 4) + j;
        w2f[o2] = f2bf(fc2w[(size_t)layer * 32768 + d * 256 + m]);
    }
}

// ---------------------------------------------------------------- prep0: lift + LN-stats + partials
// block: 64 tokens. writes H rows, stats (mu,rstd), P1p[b,nblk,d]=sum h*rstd, P2p=sum mu*rstd
__global__ __launch_bounds__(256) void prep0_kernel(const float* __restrict__ x,
        const float* __restrict__ lw, const float* __restrict__ lb,
        float* __restrict__ H, float2* __restrict__ stats,
        float* __restrict__ P1p, float* __restrict__ P2p) {
    __shared__ char lds[33280];
    float* rst = (float*)(lds + 32768);
    float* mrs = (float*)(lds + 32768 + 256);
    int b = blockIdx.y, nblk = blockIdx.x, t0 = nblk * 64, tid = threadIdx.x;

    #pragma unroll
    for (int it = 0; it < 8; ++it) {
        int idx = it * 256 + tid;
        int r = idx >> 5, d0 = (idx & 31) * 4;
        int l = t0 + r;
        float x0 = x[(size_t)b * 3072 + l];
        float x1 = x[(size_t)b * 3072 + 1024 + l];
        float x2 = x[(size_t)b * 3072 + 2048 + l];
        float coord = (float)l * (1.0f / 1023.0f);
        f32x4 hv;
        #pragma unroll
        for (int q = 0; q < 4; ++q) {
            int d = d0 + q;
            float4 w = *(const float4*)(lw + d * 4);
            hv[q] = lb[d] + w.x * x0 + w.y * x1 + w.z * x2 + w.w * coord;
        }
        *(f32x4*)(H + ((size_t)b * 1024 + l) * 128 + d0) = hv;
        int byte = r * 512 + ((d0 * 4) ^ ((r & 7) << 4));
        *(f32x4*)(lds + byte) = hv;
    }
    __syncthreads();
    {
        int t = tid >> 2, q = tid & 3;
        float s = 0.f, sq = 0.f;
        #pragma unroll
        for (int dd = 0; dd < 32; dd += 4) {
            int d = q * 32 + dd;
            int byte = t * 512 + ((d * 4) ^ ((t & 7) << 4));
            f32x4 v = *(const f32x4*)(lds + byte);
            s += v[0] + v[1] + v[2] + v[3];
            sq += v[0]*v[0] + v[1]*v[1] + v[2]*v[2] + v[3]*v[3];
        }
        s += __shfl_xor(s, 1, 64); sq += __shfl_xor(sq, 1, 64);
        s += __shfl_xor(s, 2, 64); sq += __shfl_xor(sq, 2, 64);
        if (q == 0) {
            float mu = s * (1.f / 128.f);
            float var = sq * (1.f / 128.f) - mu * mu;
            float rs = rsqrtf(var + EPSF);
            stats[(size_t)b * 1024 + t0 + t] = make_float2(mu, rs);
            rst[t] = rs; mrs[t] = mu * rs;
        }
    }
    __syncthreads();
    if (tid < 128) {
        float s = 0.f;
        #pragma unroll 8
        for (int t = 0; t < 64; ++t) {
            int byte = t * 512 + ((tid * 4) ^ ((t & 7) << 4));
            s += *(const float*)(lds + byte) * rst[t];
        }
        P1p[((size_t)b * 16 + nblk) * 128 + tid] = s;
    } else if (tid == 128) {
        float s = 0.f;
        for (int t = 0; t < 64; ++t) s += mrs[t];
        P2p[b * 16 + nblk] = s;
    }
}

// ---------------------------------------------------------------- C[b,h] from partials (k=0 Haar row)
__global__ __launch_bounds__(128) void c_kernel(const float* __restrict__ theta0,
        const float* __restrict__ P1p, const float* __restrict__ P2p,
        const float* __restrict__ lng, const float* __restrict__ lnb,
        float* __restrict__ C) {
    __shared__ float zsum[128];
    int b = blockIdx.x, t = threadIdx.x;
    float s = 0.f;
    #pragma unroll
    for (int j = 0; j < 16; ++j) s += P1p[((size_t)b * 16 + j) * 128 + t];
    float p2 = 0.f;
    #pragma unroll
    for (int j = 0; j < 16; ++j) p2 += P2p[b * 16 + j];
    zsum[t] = lng[t] * (s - p2) + 1024.0f * lnb[t];
    __syncthreads();
    const float* th = theta0 + t * 128;
    float acc = 0.f;
    #pragma unroll 8
    for (int d = 0; d < 128; d += 4) {
        float4 tv = *(const float4*)(th + d);
        acc += tv.x * zsum[d] + tv.y * zsum[d+1] + tv.z * zsum[d+2] + tv.w * zsum[d+3];
    }
    C[b * 128 + t] = acc * (1.0f / 32.0f);
}

// ---------------------------------------------------------------- mega: LN->dz->S(MFMA)->fc1->GELU->fc2->residual->(stats|head)
// LDS: region0 [0,32768): dz (23552B) then H1/Ht ; region1 [32768,49152): S tile / rst / pp
template<int LAST>
__global__ __launch_bounds__(256) void mega_kernel(
        const float* __restrict__ Hin, const float2* __restrict__ stin,
        const float* __restrict__ lng,
        const u16* __restrict__ thf, const float* __restrict__ Cb_,
        const u16* __restrict__ w1f, const float* __restrict__ b1,
        const u16* __restrict__ w2f, const float* __restrict__ b2,
        float* __restrict__ Hout, float2* __restrict__ stout,
        float* __restrict__ P1p, float* __restrict__ P2p,
        const float* __restrict__ hwp, const float* __restrict__ hbp,
        float* __restrict__ out) {
    __shared__ char lds[49152];
    int b = blockIdx.y, nblk = blockIdx.x, n0 = nblk * 64, tid = threadIdx.x;
    const float inv_s2 = 0.70710678118654752f;

    // ---- Phase A: dz staging with LN on the fly (beta cancels; gamma folded)
    const float* Hb = Hin + (size_t)b * 1024 * 128;
    const float2* stb = stin + (size_t)b * 1024;
    for (int c = tid; c < 92 * 16; c += 256) {
        int r = c >> 4, d0 = (c & 15) * 8;
        int gr = (n0 + r) & 1023, g1 = (n0 + r + 1) & 1023;
        const float* ha = Hb + (size_t)gr * 128 + d0;
        const float* hc = Hb + (size_t)g1 * 128 + d0;
        float2 sa = stb[gr], sb = stb[g1];
        u16 tmp[8];
        #pragma unroll
        for (int j = 0; j < 8; ++j) {
            float za = (ha[j] - sa.x) * sa.y;
            float zc = (hc[j] - sb.x) * sb.y;
            tmp[j] = f2bf((za - zc) * inv_s2 * lng[d0 + j]);
        }
        int byte = r * 256 + ((d0 * 2) ^ ((r & 7) << 4));
        *(bf16x8*)(lds + byte) = *(bf16x8*)tmp;
    }
    __syncthreads();

    int wave = tid >> 6, lane = tid & 63;
    int lm = lane & 15, lk = (lane >> 4) * 8;
    int hw0 = (wave & 1) * 64, tw0 = (wave >> 1) * 32;
    f32x4 zero4 = {0.f, 0.f, 0.f, 0.f};

    // ---- Phase B: S MFMA. A-frags stream from global (frag-linear, coalesced). No barriers.
    f32x4 acc[4][2];
    #pragma unroll
    for (int mt = 0; mt < 4; ++mt)
        #pragma unroll
        for (int nt = 0; nt < 2; ++nt) acc[mt][nt] = zero4;
    {
        const u16* thl = thf + (size_t)lane * 8;
        int fb = (wave & 1) * 4;
        for (int kk = 0; kk < 15; ++kk) {
            #pragma unroll
            for (int c4 = 0; c4 < 4; ++c4) {
                bf16x8 afr[4], bfr[2];
                #pragma unroll
                for (int mt = 0; mt < 4; ++mt)
                    afr[mt] = *(const bf16x8*)(thl + (size_t)((((kk * 8 + fb + mt) * 4 + c4)) << 9));
                #pragma unroll
                for (int nt = 0; nt < 2; ++nt) {
                    int trow = tw0 + nt * 16 + lm + 2 * kk;
                    int byte = trow * 256 + (((c4 * 32 + lk) * 2) ^ ((trow & 7) << 4));
                    bfr[nt] = *(const bf16x8*)(lds + byte);
                }
                #pragma unroll
                for (int mt = 0; mt < 4; ++mt)
                    #pragma unroll
                    for (int nt = 0; nt < 2; ++nt)
                        acc[mt][nt] = __builtin_amdgcn_mfma_f32_16x16x32_bf16(
                            afr[mt], bfr[nt], acc[mt][nt], 0, 0, 0);
            }
        }
    }

    // ---- Phase C: S epilogue (+C), bf16 into S tile
    {
        const float* Crow = Cb_ + b * 128;
        #pragma unroll
        for (int mt = 0; mt < 4; ++mt) {
            int h0 = hw0 + mt * 16 + (lane >> 4) * 4;
            f32x4 cv = *(const f32x4*)(Crow + h0);
            #pragma unroll
            for (int nt = 0; nt < 2; ++nt) {
                int tl = tw0 + nt * 16 + lm;
                u16 o[4];
                #pragma unroll
                for (int r = 0; r < 4; ++r) o[r] = f2bf(acc[mt][nt][r] + cv[r]);
                int byte = 32768 + tl * 256 + ((h0 * 2) ^ ((tl & 7) << 4));
                *(bf16x4*)(lds + byte) = *(bf16x4*)o;
            }
        }
    }
    __syncthreads();

    // ---- Phase D: fc1 (A from global w1f), Phase E: GELU -> H1 (region0)
    {
        f32x4 acc1[4][4];
        #pragma unroll
        for (int mt = 0; mt < 4; ++mt)
            #pragma unroll
            for (int nt = 0; nt < 4; ++nt) acc1[mt][nt] = zero4;
        const u16* w1l = w1f + (size_t)lane * 8;
        #pragma unroll
        for (int c4 = 0; c4 < 4; ++c4) {
            bf16x8 afr[4], bfr[4];
            #pragma unroll
            for (int mt = 0; mt < 4; ++mt)
                afr[mt] = *(const bf16x8*)(w1l + (size_t)(((wave * 4 + mt) * 4 + c4) << 9));
            #pragma unroll
            for (int nt = 0; nt < 4; ++nt) {
                int tl = nt * 16 + lm;
                int byte = 32768 + tl * 256 + (((c4 * 32 + lk) * 2) ^ ((tl & 7) << 4));
                bfr[nt] = *(const bf16x8*)(lds + byte);
            }
            #pragma unroll
            for (int mt = 0; mt < 4; ++mt)
                #pragma unroll
                for (int nt = 0; nt < 4; ++nt)
                    acc1[mt][nt] = __builtin_amdgcn_mfma_f32_16x16x32_bf16(
                        afr[mt], bfr[nt], acc1[mt][nt], 0, 0, 0);
        }
        #pragma unroll
        for (int mt = 0; mt < 4; ++mt) {
            int mo = wave * 64 + mt * 16 + (lane >> 4) * 4;
            f32x4 bb4 = *(const f32x4*)(b1 + mo);
            #pragma unroll
            for (int nt = 0; nt < 4; ++nt) {
                int tl = nt * 16 + lm;
                u16 o[4];
                #pragma unroll
                for (int r = 0; r < 4; ++r) {
                    float xv = acc1[mt][nt][r] + bb4[r];
                    o[r] = f2bf(0.5f * xv * (1.0f + erff(xv * 0.70710678118654752f)));
                }
                int byte = tl * 512 + ((mo * 2) ^ ((tl & 7) << 4));
                *(bf16x4*)(lds + byte) = *(bf16x4*)o;
            }
        }
    }
    __syncthreads();

    // ---- Phase F: fc2 (A from global w2f)
    f32x4 acc2[2][4];
    #pragma unroll
    for (int mt = 0; mt < 2; ++mt)
        #pragma unroll
        for (int nt = 0; nt < 4; ++nt) acc2[mt][nt] = zero4;
    {
        const u16* w2l = w2f + (size_t)lane * 8;
        #pragma unroll
        for (int c8 = 0; c8 < 8; ++c8) {
            bf16x8 afr[2], bfr[4];
            #pragma unroll
            for (int mt = 0; mt < 2; ++mt)
                afr[mt] = *(const bf16x8*)(w2l + (size_t)(((wave * 2 + mt) * 8 + c8) << 9));
            #pragma unroll
            for (int nt = 0; nt < 4; ++nt) {
                int tl = nt * 16 + lm;
                int byte = tl * 512 + (((c8 * 32 + lk) * 2) ^ ((tl & 7) << 4));
                bfr[nt] = *(const bf16x8*)(lds + byte);
            }
            #pragma unroll
            for (int mt = 0; mt < 2; ++mt)
                #pragma unroll
                for (int nt = 0; nt < 4; ++nt)
                    acc2[mt][nt] = __builtin_amdgcn_mfma_f32_16x16x32_bf16(
                        afr[mt], bfr[nt], acc2[mt][nt], 0, 0, 0);
        }
    }
    __syncthreads();

    // ---- Phase G: fc2 result f32 -> region0 [t][d]
    #pragma unroll
    for (int mt = 0; mt < 2; ++mt) {
        int dbase = wave * 32 + mt * 16 + (lane >> 4) * 4;
        #pragma unroll
        for (int nt = 0; nt < 4; ++nt) {
            int tl = nt * 16 + lm;
            int byte = tl * 512 + ((dbase * 4) ^ ((tl & 7) << 4));
            *(f32x4*)(lds + byte) = acc2[mt][nt];
        }
    }
    __syncthreads();

    // ---- Phase H: residual writeback (+ head partials if LAST)
    float* pp = (float*)(lds + 32768);
    {
        const float* Hrow = Hin + ((size_t)b * 1024 + n0) * 128;
        float* Horow = Hout + ((size_t)b * 1024 + n0) * 128;
        #pragma unroll
        for (int it = 0; it < 8; ++it) {
            int idx = it * 256 + tid;
            int r = idx >> 5, d0 = (idx & 31) * 4;
            int byte = r * 512 + ((d0 * 4) ^ ((r & 7) << 4));
            f32x4 v = *(const f32x4*)(lds + byte);
            f32x4 bb = *(const f32x4*)(b2 + d0);
            f32x4 hv = *(const f32x4*)(Hrow + (size_t)r * 128 + d0);
            hv = hv + v + bb;
            if (LAST) {
                f32x4 wv = *(const f32x4*)(hwp + d0);
                pp[r * 32 + (idx & 31)] = hv[0]*wv[0] + hv[1]*wv[1] + hv[2]*wv[2] + hv[3]*wv[3];
            } else {
                *(f32x4*)(Horow + (size_t)r * 128 + d0) = hv;
                *(f32x4*)(lds + byte) = hv;
            }
        }
    }
    __syncthreads();

    if (LAST) {
        if (tid < 64) {
            float s = 0.f;
            #pragma unroll 8
            for (int q = 0; q < 32; ++q) s += pp[tid * 32 + q];
            out[(size_t)b * 1024 + n0 + tid] = s + hbp[0];
        }
    } else {
        // ---- Phase I: next-layer LN stats for our 64 tokens
        float* rst = (float*)(lds + 32768);
        float* mrs = (float*)(lds + 32768 + 256);
        {
            int t = tid >> 2, q = tid & 3;
            float s = 0.f, sq = 0.f;
            #pragma unroll
            for (int dd = 0; dd < 32; dd += 4) {
                int d = q * 32 + dd;
                int byte = t * 512 + ((d * 4) ^ ((t & 7) << 4));
                f32x4 v = *(const f32x4*)(lds + byte);
                s += v[0] + v[1] + v[2] + v[3];
                sq += v[0]*v[0] + v[1]*v[1] + v[2]*v[2] + v[3]*v[3];
            }
            s += __shfl_xor(s, 1, 64); sq += __shfl_xor(sq, 1, 64);
            s += __shfl_xor(s, 2, 64); sq += __shfl_xor(sq, 2, 64);
            if (q == 0) {
                float mu = s * (1.f / 128.f);
                float var = sq * (1.f / 128.f) - mu * mu;
                float rs = rsqrtf(var + EPSF);
                stout[(size_t)b * 1024 + n0 + t] = make_float2(mu, rs);
                rst[t] = rs; mrs[t] = mu * rs;
            }
        }
        __syncthreads();
        // ---- Phase J: partial column sums for next-layer C
        if (tid < 128) {
            float s = 0.f;
            #pragma unroll 8
            for (int t = 0; t < 64; ++t) {
                int byte = t * 512 + ((tid * 4) ^ ((t & 7) << 4));
                s += *(const float*)(lds + byte) * rst[t];
            }
            P1p[((size_t)b * 16 + nblk) * 128 + tid] = s;
        } else if (tid == 128) {
            float s = 0.f;
            for (int t = 0; t < 64; ++t) s += mrs[t];
            P2p[b * 16 + nblk] = s;
        }
    }
}

// ----------------------------------------------------------------
extern "C" void kernel_launch(void* const* d_in, const int* in_sizes, int n_in,
                              void* d_out, int out_size, void* d_ws, size_t ws_size,
                              hipStream_t stream) {
    const float* x     = (const float*)d_in[0];
    const float* lw    = (const float*)d_in[1];
    const float* lb    = (const float*)d_in[2];
    // d_in[3] = Phi_f — analytically eliminated (Haar top-16 = const + finest 2-tap wavelets)
    const float* theta = (const float*)d_in[4];
    const float* ln_g  = (const float*)d_in[5];
    const float* ln_b  = (const float*)d_in[6];
    const float* fc1w  = (const float*)d_in[7];
    const float* fc1b  = (const float*)d_in[8];
    const float* fc2w  = (const float*)d_in[9];
    const float* fc2b  = (const float*)d_in[10];
    const float* hw    = (const float*)d_in[11];
    const float* hb    = (const float*)d_in[12];

    float* ws = (float*)d_ws;
    float* H_A = ws;                                   // 2M f32
    float* H_B = H_A + (size_t)BL * DD;                // 2M f32
    float2* st_A = (float2*)(H_B + (size_t)BL * DD);   // 16384 float2
    float2* st_B = st_A + BL;
    float* P1p = (float*)(st_B + BL);                  // 16*16*128
    float* P2p = P1p + 16 * 16 * 128;                  // 256
    float* Cb  = P2p + 256;                            // 2048
    u16* thf = (u16*)(Cb + 2048);                      // N_TH
    u16* w1f = thf + N_TH;                             // N_W1
    u16* w2f = w1f + N_W1;                             // N_W2

    cvt_kernel<<<(N_TH + N_W1 + N_W2) / 256, 256, 0, stream>>>(theta, fc1w, fc2w, thf, w1f, w2f);
    prep0_kernel<<<dim3(16, 16), 256, 0, stream>>>(x, lw, lb, H_A, st_A, P1p, P2p);

    float* Hi = H_A; float* Ho = H_B;
    float2* sti = st_A; float2* sto = st_B;
    for (int i = 0; i < NDEPTH; ++i) {
        c_kernel<<<16, 128, 0, stream>>>(theta + (size_t)i * 16 * 16384, P1p, P2p,
                                         ln_g + i * 128, ln_b + i * 128, Cb);
        if (i < NDEPTH - 1) {
            mega_kernel<0><<<dim3(16, 16), 256, 0, stream>>>(
                Hi, sti, ln_g + i * 128,
                thf + (size_t)i * 15 * 16384, Cb,
                w1f + (size_t)i * 32768, fc1b + i * 256,
                w2f + (size_t)i * 32768, fc2b + i * 128,
                Ho, sto, P1p, P2p, hw, hb, (float*)d_out);
        } else {
            mega_kernel<1><<<dim3(16, 16), 256, 0, stream>>>(
                Hi, sti, ln_g + i * 128,
                thf + (size_t)i * 15 * 16384, Cb,
                w1f + (size_t)i * 32768, fc1b + i * 256,
                w2f + (size_t)i * 32768, fc2b + i * 128,
                Ho, sto, P1p, P2p, hw, hb, (float*)d_out);
        }
        float* tH = Hi; Hi = Ho; Ho = tH;
        float2* tS = sti; sti = sto; sto = tS;
    }
}

// Round 4
// 141.011 us; speedup vs baseline: 5.9458x; 1.7314x over previous
//
#include <hip/hip_runtime.h>
#include <math.h>

#define BB 16
#define LL 1024
#define DD 128
#define BL (BB*LL)
#define NDEPTH 4
#define EPSF 1e-5f

typedef unsigned short u16;
typedef short bf16x8 __attribute__((ext_vector_type(8)));
typedef short bf16x4 __attribute__((ext_vector_type(4)));
typedef float f32x4 __attribute__((ext_vector_type(4)));

static __device__ __forceinline__ u16 f2bf(float x) {
    unsigned u = __float_as_uint(x);
    u = u + 0x7fffu + ((u >> 16) & 1u);
    return (u16)(u >> 16);
}

// LDS layout (mega): dz 60 rows x 256B | S 32 x 256B | H1/Ht 32 x 512B | rst/mrs
#define DZ_B 0
#define S_B  15360
#define H1_B 23552
#define RST_B 39936
#define MRS_B 40064
#define LDS_TOT 40192

// ---------------------------------------------------------------- combined weight convert
// theta -> frag-linear bf16 [slab=layer*15+kk][f:8][c:4][lane:64][8]
//   value = theta[layer][kk+1][h=f*16+(ln&15)][d=32c+8*(ln>>4)+j]
// w1 -> [layer][f:16][c:4][lane][8]  = fc1w[layer][m=f*16+lm][d=32c+8hi+j]
// w2 -> [layer][f:8][c:8][lane][8]   = fc2w[layer][d=f*16+lm][m=32c+8hi+j]
#define N_TH (4*15*16384)
#define N_W1 (4*32768)
#define N_W2 (4*32768)
__global__ __launch_bounds__(256) void cvt_kernel(const float* __restrict__ theta,
        const float* __restrict__ fc1w, const float* __restrict__ fc2w,
        u16* __restrict__ thf, u16* __restrict__ w1f, u16* __restrict__ w2f) {
    int o = blockIdx.x * 256 + threadIdx.x;
    if (o < N_TH) {
        int j = o & 7, ln = (o >> 3) & 63, c = (o >> 9) & 3, f = (o >> 11) & 7;
        int slab = o >> 14;
        int layer = slab / 15, kk = slab - layer * 15;
        int h = f * 16 + (ln & 15), d = 32 * c + 8 * (ln >> 4) + j;
        thf[o] = f2bf(theta[(((size_t)layer * 16 + kk + 1) * 128 + h) * 128 + d]);
    } else if (o < N_TH + N_W1) {
        int o2 = o - N_TH;
        int j = o2 & 7, ln = (o2 >> 3) & 63, c = (o2 >> 9) & 3, f = (o2 >> 11) & 15;
        int layer = o2 >> 15;
        int m = f * 16 + (ln & 15), d = 32 * c + 8 * (ln >> 4) + j;
        w1f[o2] = f2bf(fc1w[(size_t)layer * 32768 + m * 128 + d]);
    } else if (o < N_TH + N_W1 + N_W2) {
        int o2 = o - (N_TH + N_W1);
        int j = o2 & 7, ln = (o2 >> 3) & 63, c = (o2 >> 9) & 7, f = (o2 >> 12) & 7;
        int layer = o2 >> 15;
        int d = f * 16 + (ln & 15), m = 32 * c + 8 * (ln >> 4) + j;
        w2f[o2] = f2bf(fc2w[(size_t)layer * 32768 + d * 256 + m]);
    }
}

// ---------------------------------------------------------------- prep0: lift + LN-stats + partials
// block: 32 tokens, 512 threads. grid (32, 16).
__global__ __launch_bounds__(512) void prep0_kernel(const float* __restrict__ x,
        const float* __restrict__ lw, const float* __restrict__ lb,
        float* __restrict__ H, float2* __restrict__ stats,
        float* __restrict__ P1p, float* __restrict__ P2p) {
    __shared__ char lds[16384 + 256];
    float* rst = (float*)(lds + 16384);
    float* mrs = (float*)(lds + 16384 + 128);
    int b = blockIdx.y, nblk = blockIdx.x, t0 = nblk * 32, tid = threadIdx.x;

    #pragma unroll
    for (int it = 0; it < 2; ++it) {
        int idx = it * 512 + tid;
        int r = idx >> 5, d0 = (idx & 31) * 4;
        int l = t0 + r;
        float x0 = x[(size_t)b * 3072 + l];
        float x1 = x[(size_t)b * 3072 + 1024 + l];
        float x2 = x[(size_t)b * 3072 + 2048 + l];
        float coord = (float)l * (1.0f / 1023.0f);
        f32x4 hv;
        #pragma unroll
        for (int q = 0; q < 4; ++q) {
            int d = d0 + q;
            float4 w = *(const float4*)(lw + d * 4);
            hv[q] = lb[d] + w.x * x0 + w.y * x1 + w.z * x2 + w.w * coord;
        }
        *(f32x4*)(H + ((size_t)b * 1024 + l) * 128 + d0) = hv;
        int byte = r * 512 + ((d0 * 4) ^ ((r & 7) << 4));
        *(f32x4*)(lds + byte) = hv;
    }
    __syncthreads();
    {
        int t = tid >> 4, q = tid & 15;
        float s = 0.f, sq = 0.f;
        #pragma unroll
        for (int dd = 0; dd < 8; dd += 4) {
            int d = q * 8 + dd;
            int byte = t * 512 + ((d * 4) ^ ((t & 7) << 4));
            f32x4 v = *(const f32x4*)(lds + byte);
            s += v[0] + v[1] + v[2] + v[3];
            sq += v[0]*v[0] + v[1]*v[1] + v[2]*v[2] + v[3]*v[3];
        }
        #pragma unroll
        for (int o = 1; o < 16; o <<= 1) {
            s += __shfl_xor(s, o, 64); sq += __shfl_xor(sq, o, 64);
        }
        if (q == 0) {
            float mu = s * (1.f / 128.f);
            float var = sq * (1.f / 128.f) - mu * mu;
            float rs = rsqrtf(var + EPSF);
            stats[(size_t)b * 1024 + t0 + t] = make_float2(mu, rs);
            rst[t] = rs; mrs[t] = mu * rs;
        }
    }
    __syncthreads();
    if (tid < 128) {
        float s = 0.f;
        #pragma unroll 8
        for (int t = 0; t < 32; ++t) {
            int byte = t * 512 + ((tid * 4) ^ ((t & 7) << 4));
            s += *(const float*)(lds + byte) * rst[t];
        }
        P1p[((size_t)b * 32 + nblk) * 128 + tid] = s;
    } else if (tid == 128) {
        float s = 0.f;
        for (int t = 0; t < 32; ++t) s += mrs[t];
        P2p[b * 32 + nblk] = s;
    }
}

// ---------------------------------------------------------------- C[b,h] (k=0 Haar row), grid (16 b, 8 hc)
__global__ __launch_bounds__(128) void c_kernel(const float* __restrict__ theta0,
        const float* __restrict__ P1p, const float* __restrict__ P2p,
        const float* __restrict__ lng, const float* __restrict__ lnb,
        float* __restrict__ C) {
    __shared__ float zsum[128];
    int b = blockIdx.x, hc = blockIdx.y, tid = threadIdx.x;
    float s = 0.f;
    #pragma unroll 8
    for (int j = 0; j < 32; ++j) s += P1p[((size_t)b * 32 + j) * 128 + tid];
    float p2 = 0.f;
    #pragma unroll 8
    for (int j = 0; j < 32; ++j) p2 += P2p[b * 32 + j];
    zsum[tid] = lng[tid] * (s - p2) + 1024.0f * lnb[tid];
    __syncthreads();
    int h = hc * 16 + (tid >> 3), q = tid & 7;
    const float* th = theta0 + h * 128 + q * 16;
    float acc = 0.f;
    #pragma unroll
    for (int d = 0; d < 16; d += 4) {
        float4 tv = *(const float4*)(th + d);
        acc += tv.x * zsum[q*16 + d] + tv.y * zsum[q*16 + d + 1]
             + tv.z * zsum[q*16 + d + 2] + tv.w * zsum[q*16 + d + 3];
    }
    acc += __shfl_xor(acc, 1, 64);
    acc += __shfl_xor(acc, 2, 64);
    acc += __shfl_xor(acc, 4, 64);
    if (q == 0) C[b * 128 + h] = acc * (1.0f / 32.0f);
}

// ---------------------------------------------------------------- mega: LN->dz->S(MFMA)->fc1->GELU->fc2->residual->(stats|head)
// 512 threads (8 waves), 32-token tile, grid (32, 16) = 512 blocks = 2/CU.
template<int LAST>
__global__ __launch_bounds__(512, 4) void mega_kernel(
        const float* __restrict__ Hin, const float2* __restrict__ stin,
        const float* __restrict__ lng,
        const u16* __restrict__ thf, const float* __restrict__ Cb_,
        const u16* __restrict__ w1f, const float* __restrict__ b1,
        const u16* __restrict__ w2f, const float* __restrict__ b2,
        float* __restrict__ Hout, float2* __restrict__ stout,
        float* __restrict__ P1p, float* __restrict__ P2p,
        const float* __restrict__ hwp, const float* __restrict__ hbp,
        float* __restrict__ out) {
    __shared__ char lds[LDS_TOT];
    int b = blockIdx.y, nblk = blockIdx.x, n0 = nblk * 32, tid = threadIdx.x;
    const float inv_s2 = 0.70710678118654752f;

    // ---- Phase A: dz staging with LN on the fly (beta cancels; gamma folded). 60 halo rows.
    const float* Hb = Hin + (size_t)b * 1024 * 128;
    const float2* stb = stin + (size_t)b * 1024;
    for (int c = tid; c < 60 * 16; c += 512) {
        int r = c >> 4, d0 = (c & 15) * 8;
        int gr = (n0 + r) & 1023, g1 = (n0 + r + 1) & 1023;
        const float* ha = Hb + (size_t)gr * 128 + d0;
        const float* hc = Hb + (size_t)g1 * 128 + d0;
        float2 sa = stb[gr], sb = stb[g1];
        u16 tmp[8];
        #pragma unroll
        for (int j = 0; j < 8; ++j) {
            float za = (ha[j] - sa.x) * sa.y;
            float zc = (hc[j] - sb.x) * sb.y;
            tmp[j] = f2bf((za - zc) * inv_s2 * lng[d0 + j]);
        }
        int byte = r * 256 + ((d0 * 2) ^ ((r & 7) << 4));
        *(bf16x8*)(lds + byte) = *(bf16x8*)tmp;
    }
    __syncthreads();

    int wave = tid >> 6, lane = tid & 63;
    int lm = lane & 15, lk = (lane >> 4) * 8;
    int fb = (wave & 3) * 2;            // S: wave h-frags {fb, fb+1}
    int tw0 = (wave >> 2) * 16;         // S: wave t-frag
    f32x4 zero4 = {0.f, 0.f, 0.f, 0.f};

    // ---- Phase B: S MFMA. A-frags stream from global (frag-linear). No barriers.
    f32x4 accS[2] = {zero4, zero4};
    {
        const u16* thl = thf + (size_t)lane * 8;
        #pragma unroll 4
        for (int it = 0; it < 60; ++it) {
            int kk = it >> 2, c4 = it & 3;
            bf16x8 afr0 = *(const bf16x8*)(thl + ((size_t)((kk * 8 + fb + 0) * 4 + c4) << 9));
            bf16x8 afr1 = *(const bf16x8*)(thl + ((size_t)((kk * 8 + fb + 1) * 4 + c4) << 9));
            int trow = tw0 + lm + 2 * kk;
            int byte = trow * 256 + (((c4 * 32 + lk) * 2) ^ ((trow & 7) << 4));
            bf16x8 bfr = *(const bf16x8*)(lds + byte);
            accS[0] = __builtin_amdgcn_mfma_f32_16x16x32_bf16(afr0, bfr, accS[0], 0, 0, 0);
            accS[1] = __builtin_amdgcn_mfma_f32_16x16x32_bf16(afr1, bfr, accS[1], 0, 0, 0);
        }
    }

    // ---- Phase C: S epilogue (+C), bf16 into S tile
    {
        const float* Crow = Cb_ + b * 128;
        int tl = tw0 + lm;
        #pragma unroll
        for (int mt = 0; mt < 2; ++mt) {
            int h0 = (fb + mt) * 16 + (lane >> 4) * 4;
            f32x4 cv = *(const f32x4*)(Crow + h0);
            u16 o[4];
            #pragma unroll
            for (int r = 0; r < 4; ++r) o[r] = f2bf(accS[mt][r] + cv[r]);
            int byte = S_B + tl * 256 + ((h0 * 2) ^ ((tl & 7) << 4));
            *(bf16x4*)(lds + byte) = *(bf16x4*)o;
        }
    }
    __syncthreads();

    // ---- Phase D: fc1 (A from global w1f) + GELU -> H1
    {
        f32x4 acc1[2][2];
        #pragma unroll
        for (int mt = 0; mt < 2; ++mt)
            #pragma unroll
            for (int nt = 0; nt < 2; ++nt) acc1[mt][nt] = zero4;
        const u16* w1l = w1f + (size_t)lane * 8;
        #pragma unroll
        for (int c4 = 0; c4 < 4; ++c4) {
            bf16x8 afr[2], bfr[2];
            #pragma unroll
            for (int mt = 0; mt < 2; ++mt)
                afr[mt] = *(const bf16x8*)(w1l + ((size_t)((wave * 2 + mt) * 4 + c4) << 9));
            #pragma unroll
            for (int nt = 0; nt < 2; ++nt) {
                int tl = nt * 16 + lm;
                int byte = S_B + tl * 256 + (((c4 * 32 + lk) * 2) ^ ((tl & 7) << 4));
                bfr[nt] = *(const bf16x8*)(lds + byte);
            }
            #pragma unroll
            for (int mt = 0; mt < 2; ++mt)
                #pragma unroll
                for (int nt = 0; nt < 2; ++nt)
                    acc1[mt][nt] = __builtin_amdgcn_mfma_f32_16x16x32_bf16(
                        afr[mt], bfr[nt], acc1[mt][nt], 0, 0, 0);
        }
        #pragma unroll
        for (int mt = 0; mt < 2; ++mt) {
            int mo = wave * 32 + mt * 16 + (lane >> 4) * 4;
            f32x4 bb4 = *(const f32x4*)(b1 + mo);
            #pragma unroll
            for (int nt = 0; nt < 2; ++nt) {
                int tl = nt * 16 + lm;
                u16 o[4];
                #pragma unroll
                for (int r = 0; r < 4; ++r) {
                    float xv = acc1[mt][nt][r] + bb4[r];
                    o[r] = f2bf(0.5f * xv * (1.0f + erff(xv * 0.70710678118654752f)));
                }
                int byte = H1_B + tl * 512 + ((mo * 2) ^ ((tl & 7) << 4));
                *(bf16x4*)(lds + byte) = *(bf16x4*)o;
            }
        }
    }
    __syncthreads();

    // ---- Phase F: fc2 (A from global w2f)
    f32x4 acc2[2] = {zero4, zero4};
    {
        const u16* w2l = w2f + (size_t)lane * 8;
        #pragma unroll
        for (int c8 = 0; c8 < 8; ++c8) {
            bf16x8 afr = *(const bf16x8*)(w2l + ((size_t)(wave * 8 + c8) << 9));
            #pragma unroll
            for (int nt = 0; nt < 2; ++nt) {
                int tl = nt * 16 + lm;
                int byte = H1_B + tl * 512 + (((c8 * 32 + lk) * 2) ^ ((tl & 7) << 4));
                bf16x8 bfr = *(const bf16x8*)(lds + byte);
                acc2[nt] = __builtin_amdgcn_mfma_f32_16x16x32_bf16(afr, bfr, acc2[nt], 0, 0, 0);
            }
        }
    }
    __syncthreads();

    // ---- Phase G: fc2 result f32 -> [t][d] tile (reuse H1 region)
    {
        int dbase = wave * 16 + (lane >> 4) * 4;
        #pragma unroll
        for (int nt = 0; nt < 2; ++nt) {
            int tl = nt * 16 + lm;
            int byte = H1_B + tl * 512 + ((dbase * 4) ^ ((tl & 7) << 4));
            *(f32x4*)(lds + byte) = acc2[nt];
        }
    }
    __syncthreads();

    // ---- Phase H: residual writeback (+ head if LAST)
    {
        const float* Hrow = Hin + ((size_t)b * 1024 + n0) * 128;
        float* Horow = Hout + ((size_t)b * 1024 + n0) * 128;
        #pragma unroll
        for (int it = 0; it < 2; ++it) {
            int idx = it * 512 + tid;
            int r = idx >> 5, d0 = (idx & 31) * 4;
            int byte = H1_B + r * 512 + ((d0 * 4) ^ ((r & 7) << 4));
            f32x4 v = *(const f32x4*)(lds + byte);
            f32x4 bb = *(const f32x4*)(b2 + d0);
            f32x4 hv = *(const f32x4*)(Hrow + (size_t)r * 128 + d0);
            hv = hv + v + bb;
            if (LAST) {
                f32x4 wv = *(const f32x4*)(hwp + d0);
                float s = hv[0]*wv[0] + hv[1]*wv[1] + hv[2]*wv[2] + hv[3]*wv[3];
                #pragma unroll
                for (int o = 1; o < 32; o <<= 1) s += __shfl_xor(s, o, 64);
                if ((lane & 31) == 0) out[(size_t)b * 1024 + n0 + r] = s + hbp[0];
            } else {
                *(f32x4*)(Horow + (size_t)r * 128 + d0) = hv;
                *(f32x4*)(lds + byte) = hv;
            }
        }
    }
    if (!LAST) {
        __syncthreads();
        // ---- Phase I: next-layer LN stats
        float* rst = (float*)(lds + RST_B);
        float* mrs = (float*)(lds + MRS_B);
        {
            int t = tid >> 4, q = tid & 15;
            float s = 0.f, sq = 0.f;
            #pragma unroll
            for (int dd = 0; dd < 8; dd += 4) {
                int d = q * 8 + dd;
                int byte = H1_B + t * 512 + ((d * 4) ^ ((t & 7) << 4));
                f32x4 v = *(const f32x4*)(lds + byte);
                s += v[0] + v[1] + v[2] + v[3];
                sq += v[0]*v[0] + v[1]*v[1] + v[2]*v[2] + v[3]*v[3];
            }
            #pragma unroll
            for (int o = 1; o < 16; o <<= 1) {
                s += __shfl_xor(s, o, 64); sq += __shfl_xor(sq, o, 64);
            }
            if (q == 0) {
                float mu = s * (1.f / 128.f);
                float var = sq * (1.f / 128.f) - mu * mu;
                float rs = rsqrtf(var + EPSF);
                stout[(size_t)b * 1024 + n0 + t] = make_float2(mu, rs);
                rst[t] = rs; mrs[t] = mu * rs;
            }
        }
        __syncthreads();
        // ---- Phase J: partial column sums for next-layer C
        if (tid < 128) {
            float s = 0.f;
            #pragma unroll 8
            for (int t = 0; t < 32; ++t) {
                int byte = H1_B + t * 512 + ((tid * 4) ^ ((t & 7) << 4));
                s += *(const float*)(lds + byte) * rst[t];
            }
            P1p[((size_t)b * 32 + nblk) * 128 + tid] = s;
        } else if (tid == 128) {
            float s = 0.f;
            for (int t = 0; t < 32; ++t) s += mrs[t];
            P2p[b * 32 + nblk] = s;
        }
    }
}

// ----------------------------------------------------------------
extern "C" void kernel_launch(void* const* d_in, const int* in_sizes, int n_in,
                              void* d_out, int out_size, void* d_ws, size_t ws_size,
                              hipStream_t stream) {
    const float* x     = (const float*)d_in[0];
    const float* lw    = (const float*)d_in[1];
    const float* lb    = (const float*)d_in[2];
    // d_in[3] = Phi_f — analytically eliminated (Haar top-16 = const + finest 2-tap wavelets)
    const float* theta = (const float*)d_in[4];
    const float* ln_g  = (const float*)d_in[5];
    const float* ln_b  = (const float*)d_in[6];
    const float* fc1w  = (const float*)d_in[7];
    const float* fc1b  = (const float*)d_in[8];
    const float* fc2w  = (const float*)d_in[9];
    const float* fc2b  = (const float*)d_in[10];
    const float* hw    = (const float*)d_in[11];
    const float* hb    = (const float*)d_in[12];

    float* ws = (float*)d_ws;
    float* H_A = ws;                                   // 2M f32
    float* H_B = H_A + (size_t)BL * DD;                // 2M f32
    float2* st_A = (float2*)(H_B + (size_t)BL * DD);   // 16384 float2
    float2* st_B = st_A + BL;
    float* P1p = (float*)(st_B + BL);                  // 16*32*128
    float* P2p = P1p + 16 * 32 * 128;                  // 512
    float* Cb  = P2p + 512;                            // 2048
    u16* thf = (u16*)(Cb + 2048);                      // N_TH
    u16* w1f = thf + N_TH;                             // N_W1
    u16* w2f = w1f + N_W1;                             // N_W2

    cvt_kernel<<<(N_TH + N_W1 + N_W2) / 256, 256, 0, stream>>>(theta, fc1w, fc2w, thf, w1f, w2f);
    prep0_kernel<<<dim3(32, 16), 512, 0, stream>>>(x, lw, lb, H_A, st_A, P1p, P2p);

    float* Hi = H_A; float* Ho = H_B;
    float2* sti = st_A; float2* sto = st_B;
    for (int i = 0; i < NDEPTH; ++i) {
        c_kernel<<<dim3(16, 8), 128, 0, stream>>>(theta + (size_t)i * 16 * 16384, P1p, P2p,
                                                  ln_g + i * 128, ln_b + i * 128, Cb);
        if (i < NDEPTH - 1) {
            mega_kernel<0><<<dim3(32, 16), 512, 0, stream>>>(
                Hi, sti, ln_g + i * 128,
                thf + (size_t)i * 15 * 16384, Cb,
                w1f + (size_t)i * 32768, fc1b + i * 256,
                w2f + (size_t)i * 32768, fc2b + i * 128,
                Ho, sto, P1p, P2p, hw, hb, (float*)d_out);
        } else {
            mega_kernel<1><<<dim3(32, 16), 512, 0, stream>>>(
                Hi, sti, ln_g + i * 128,
                thf + (size_t)i * 15 * 16384, Cb,
                w1f + (size_t)i * 32768, fc1b + i * 256,
                w2f + (size_t)i * 32768, fc2b + i * 128,
                Ho, sto, P1p, P2p, hw, hb, (float*)d_out);
        }
        float* tH = Hi; Hi = Ho; Ho = tH;
        float2* tS = sti; sti = sto; sto = tS;
    }
}